// Round 19
// baseline (106.237 us; speedup 1.0000x reference)
//
#include <hip/hip_runtime.h>

#define B_ 64
#define L_ 1024
#define M_ 256
#define F_ 256
#define LSTEP 512   // grid = 512; block handles l = bid and bid+512

typedef __attribute__((ext_vector_type(8))) short short8;    // 8 bf16 (4 VGPR)
typedef __attribute__((ext_vector_type(16))) float f32x16;   // 32x32 MFMA C/D
typedef unsigned int u32;

struct Frag3 { short8 h, m, l; };

__device__ __forceinline__ u32 asu(float f) { union { float f; u32 u; } c; c.f = f; return c.u; }
__device__ __forceinline__ float asf(u32 u) { union { float f; u32 u; } c; c.u = u; return c.f; }
__device__ __forceinline__ u32 pack2(u32 lo, u32 hi) {
    return __builtin_amdgcn_perm(hi, lo, 0x07060302u);
}
__device__ __forceinline__ float4 ld4(const float* p) {
    return *reinterpret_cast<const float4*>(p);
}

// Async 16B global->LDS DMA; LDS dest wave-uniform, per-lane source carries
// the XOR swizzle (m173 pattern, validated R6/R10).
__device__ __forceinline__ void async_cp16(const float* g, float* l) {
    __builtin_amdgcn_global_load_lds(
        (const __attribute__((address_space(1))) u32*)g,
        (__attribute__((address_space(3))) u32*)l,
        16, 0, 0);
}

// Exact 3-way bf16 truncation split of 8 fp32: x = h + m + l (top 24 mantissa bits).
__device__ __forceinline__ Frag3 split8(float4 a, float4 b) {
    float x[8] = {a.x, a.y, a.z, a.w, b.x, b.y, b.z, b.w};
    u32 xb[8], rb[8], sb[8];
#pragma unroll
    for (int e = 0; e < 8; ++e) {
        xb[e] = asu(x[e]);
        float hf = asf(xb[e] & 0xFFFF0000u);
        float r  = x[e] - hf;                 // exact
        rb[e] = asu(r);
        float mf = asf(rb[e] & 0xFFFF0000u);
        float r2 = r - mf;                    // exact
        sb[e] = asu(r2);
    }
    union { u32 w[4]; short8 s; } H, M, Lo;
#pragma unroll
    for (int d = 0; d < 4; ++d) {
        H.w[d]  = pack2(xb[2 * d], xb[2 * d + 1]);
        M.w[d]  = pack2(rb[2 * d], rb[2 * d + 1]);
        Lo.w[d] = pack2(sb[2 * d], sb[2 * d + 1]);
    }
    Frag3 f; f.h = H.s; f.m = M.s; f.l = Lo.s; return f;
}

#define MFMA6(ACC, A, Bf)                                                        \
    ACC = __builtin_amdgcn_mfma_f32_32x32x16_bf16((A).m, (Bf).m, ACC, 0, 0, 0);  \
    ACC = __builtin_amdgcn_mfma_f32_32x32x16_bf16((A).h, (Bf).l, ACC, 0, 0, 0);  \
    ACC = __builtin_amdgcn_mfma_f32_32x32x16_bf16((A).l, (Bf).h, ACC, 0, 0, 0);  \
    ACC = __builtin_amdgcn_mfma_f32_32x32x16_bf16((A).h, (Bf).m, ACC, 0, 0, 0);  \
    ACC = __builtin_amdgcn_mfma_f32_32x32x16_bf16((A).m, (Bf).h, ACC, 0, 0, 0);  \
    ACC = __builtin_amdgcn_mfma_f32_32x32x16_bf16((A).h, (Bf).h, ACC, 0, 0, 0)

#define SBAR() __builtin_amdgcn_sched_barrier(0)

// R18 core + T3 fine interleave: the 5 cp16s for tile ft+1 are spread INTO
// tile ft's compute at sub-phase boundaries (not burst at the top), and one
// vmcnt(0)+s_barrier per tile replaces the barrier pair. T5 setprio wraps
// each MFMA6 cluster (role-split now exists). Epilogue barriers are raw
// s_barrier + lgkmcnt only -- the cross-staged tile-0 DMA flies through the
// epilogue un-drained. MFMA sequence identical to R18 -> absmax 0.
// D layout: col(m)=lane&31, row=(reg&3)+8*(reg>>2)+4*(lane>>5)  [m74/m101].
__launch_bounds__(512, 2)
__global__ void mq_mfma_fi_kernel(const float* __restrict__ patch,
                                  const float* __restrict__ queue,
                                  float* __restrict__ out) {
    const int l0   = blockIdx.x;
    const int t    = threadIdx.x;
    const int lane = t & 63;
    const int w    = t >> 6;        // 0..7
    const int bt   = w & 1;
    const int mtg  = w >> 1;        // 0..3
    const int r32  = lane & 31;
    const int kh   = lane >> 5;     // k-half: f-offset kh*8

    __shared__ __align__(16) float Ql[2][256 * 32];  // 2 x 32KB
    __shared__ __align__(16) float Pl[2][64 * 32];   // 2 x 8KB   (total 80KB)

    // staging geometry (R13/R18): wave w stages Q rows w*32..+31 (4 chunks)
    // and P rows w*8..+7 (1 chunk); swizzled source chunk lcol^lrow.
    const int lrow = lane >> 3;
    const int lcol = lane & 7;
    const float* qsrcw = queue + ((size_t)l0 * M_ + w * 32 + lrow) * F_ + (lcol ^ lrow) * 4;
    const float* psrcw = patch + ((size_t)(w * 8 + lrow) * L_ + l0) * F_ + (lcol ^ lrow) * 4;
    const size_t QD = (size_t)LSTEP * M_ * F_;   // Q offset l -> l+512
    const size_t PD = (size_t)LSTEP * F_;        // P offset l -> l+512

    f32x16 acc0 = (f32x16)0.f, acc1 = (f32x16)0.f;

    // prologue: stage tile 0 of l1 into buf0 (burst; nothing to interleave)
#pragma unroll
    for (int k = 0; k < 4; ++k)
        async_cp16(qsrcw + (size_t)k * 8 * F_, &Ql[0][(w * 4 + k) * 256]);
    async_cp16(psrcw, &Pl[0][w * 256]);

    const int s7  = r32 & 7;         // read-side XOR (row&7 == r32&7 everywhere)
    const int ra  = bt * 32 + r32;   // P row for this lane
    const int rb0 = mtg * 64 + r32;  // first Q row
    const int rb1 = mtg * 64 + 32 + r32;

    // epilogue scratch in buf1 (cross-staged tile 0 targets buf0)
    float* pval = (float*)&Pl[1][0];          // [4][64]
    int*   pidx = (int*)&Pl[1][0] + 256;      // [4][64]
    int*   sidx = (int*)&Pl[1][0] + 512;      // [64]

#pragma unroll
    for (int li = 0; li < 2; ++li) {
        const size_t qo = (size_t)li * QD;
        const size_t po = (size_t)li * PD;

#pragma unroll 1
        for (int ft = 0; ft < 8; ++ft) {
            // tile top: own tile-ft chunks landed; barrier doubles as
            // buffer-reuse fence (everyone past compute(ft-1)).
            asm volatile("s_waitcnt vmcnt(0)" ::: "memory");
            __builtin_amdgcn_s_barrier();
            SBAR();

            const bool dostg = (ft < 7) || (li == 0);
            const size_t qoff = (ft < 7) ? qo + (size_t)(ft + 1) * 32 : QD;
            const size_t poff = (ft < 7) ? po + (size_t)(ft + 1) * 32 : PD;
            float* Qd = (ft < 7) ? Ql[(ft + 1) & 1] : Ql[0];
            float* Pd = (ft < 7) ? Pl[(ft + 1) & 1] : Pl[0];

            const float* Qb = Ql[ft & 1];
            const float* Pb = Pl[ft & 1];

            // ---- kk = 0 ----
            {
                const int c0 = kh * 2;
                const float4 a0 = ld4(&Pb[ra * 32 + ((c0 ^ s7) * 4)]);
                const float4 a1 = ld4(&Pb[ra * 32 + (((c0 + 1) ^ s7) * 4)]);
                const Frag3 A = split8(a0, a1);
                if (dostg) async_cp16(qsrcw + qoff, &Qd[(w * 4 + 0) * 256]);
                SBAR();
                {
                    const float4 b0 = ld4(&Qb[rb0 * 32 + ((c0 ^ s7) * 4)]);
                    const float4 b1 = ld4(&Qb[rb0 * 32 + (((c0 + 1) ^ s7) * 4)]);
                    const Frag3 Bf = split8(b0, b1);
                    __builtin_amdgcn_s_setprio(1);
                    MFMA6(acc0, A, Bf);
                    __builtin_amdgcn_s_setprio(0);
                }
                if (dostg) async_cp16(qsrcw + (size_t)8 * F_ + qoff, &Qd[(w * 4 + 1) * 256]);
                SBAR();
                {
                    const float4 b0 = ld4(&Qb[rb1 * 32 + ((c0 ^ s7) * 4)]);
                    const float4 b1 = ld4(&Qb[rb1 * 32 + (((c0 + 1) ^ s7) * 4)]);
                    const Frag3 Bf = split8(b0, b1);
                    __builtin_amdgcn_s_setprio(1);
                    MFMA6(acc1, A, Bf);
                    __builtin_amdgcn_s_setprio(0);
                }
                if (dostg) async_cp16(qsrcw + (size_t)16 * F_ + qoff, &Qd[(w * 4 + 2) * 256]);
                SBAR();
            }
            // ---- kk = 1 ----
            {
                const int c0 = 4 + kh * 2;
                const float4 a0 = ld4(&Pb[ra * 32 + ((c0 ^ s7) * 4)]);
                const float4 a1 = ld4(&Pb[ra * 32 + (((c0 + 1) ^ s7) * 4)]);
                const Frag3 A = split8(a0, a1);
                if (dostg) async_cp16(qsrcw + (size_t)24 * F_ + qoff, &Qd[(w * 4 + 3) * 256]);
                SBAR();
                {
                    const float4 b0 = ld4(&Qb[rb0 * 32 + ((c0 ^ s7) * 4)]);
                    const float4 b1 = ld4(&Qb[rb0 * 32 + (((c0 + 1) ^ s7) * 4)]);
                    const Frag3 Bf = split8(b0, b1);
                    __builtin_amdgcn_s_setprio(1);
                    MFMA6(acc0, A, Bf);
                    __builtin_amdgcn_s_setprio(0);
                }
                if (dostg) async_cp16(psrcw + poff, &Pd[w * 256]);
                SBAR();
                {
                    const float4 b0 = ld4(&Qb[rb1 * 32 + ((c0 ^ s7) * 4)]);
                    const float4 b1 = ld4(&Qb[rb1 * 32 + (((c0 + 1) ^ s7) * 4)]);
                    const Frag3 Bf = split8(b0, b1);
                    __builtin_amdgcn_s_setprio(1);
                    MFMA6(acc1, A, Bf);
                    __builtin_amdgcn_s_setprio(0);
                }
                SBAR();
            }
        }

        // ---- epilogue for l = l0 + li*LSTEP. Raw barriers only (no vmcnt
        //      drain) so the cross-staged tile-0 DMA lands during this.
        __builtin_amdgcn_s_barrier();   // all waves past ft=7 compute
        SBAR();

        // argmax over m per b (numpy first-occurrence, logic as R13/R18).
#pragma unroll
        for (int r = 0; r < 16; ++r) {
            float bv = acc0[r];
            int   bi = mtg * 64 + r32;
            {
                const float cv = acc1[r];
                const int   ci = mtg * 64 + 32 + r32;
                if (cv > bv) { bv = cv; bi = ci; }
            }
#pragma unroll
            for (int off = 16; off >= 1; off >>= 1) {
                const float ov = __shfl_xor(bv, off);
                const int   oi = __shfl_xor(bi, off);
                if (ov > bv || (ov == bv && oi < bi)) { bv = ov; bi = oi; }
            }
            if (r32 == 0) {
                const int b = bt * 32 + (r & 3) + 8 * (r >> 2) + 4 * kh;
                pval[mtg * 64 + b] = bv;
                pidx[mtg * 64 + b] = bi;
            }
        }
        asm volatile("s_waitcnt lgkmcnt(0)" ::: "memory");
        __builtin_amdgcn_s_barrier();
        SBAR();

        if (t < 64) {
            float bv = pval[t];
            int   bi = pidx[t];
#pragma unroll
            for (int g = 1; g < 4; ++g) {
                const float cv = pval[g * 64 + t];
                if (cv > bv) { bv = cv; bi = pidx[g * 64 + t]; }
            }
            sidx[t] = bi;
        }
        asm volatile("s_waitcnt lgkmcnt(0)" ::: "memory");
        __builtin_amdgcn_s_barrier();
        SBAR();

        // gather: out[b][l][:] = queue[l][sidx[b]][:]
        {
            const int lcur = l0 + li * LSTEP;
            const int cb = t >> 6;     // 0..7
            const int cc = t & 63;
#pragma unroll
            for (int b0 = 0; b0 < 64; b0 += 8) {
                const int b  = b0 + cb;
                const int mi = sidx[b];
                const float4 v = ld4(&queue[((size_t)lcur * M_ + mi) * F_ + cc * 4]);
                *reinterpret_cast<float4*>(&out[((size_t)b * L_ + lcur) * F_ + cc * 4]) = v;
            }
        }

        acc0 = (f32x16)0.f;
        acc1 = (f32x16)0.f;
    }
}

extern "C" void kernel_launch(void* const* d_in, const int* in_sizes, int n_in,
                              void* d_out, int out_size, void* d_ws, size_t ws_size,
                              hipStream_t stream) {
    const float* patch = (const float*)d_in[0];
    const float* queue = (const float*)d_in[1];
    float* out = (float*)d_out;
    mq_mfma_fi_kernel<<<dim3(LSTEP), dim3(512), 0, stream>>>(patch, queue, out);
}